// Round 5
// baseline (315.658 us; speedup 1.0000x reference)
//
#include <hip/hip_runtime.h>
#include <math.h>

#define LL 384
#define NN 512
#define DIN 128
#define DOUT 64
#define HH 4
#define CC 16
#define DFF 256
#define EPS 1e-5f

typedef __attribute__((ext_vector_type(4))) float f32x4;
typedef __attribute__((ext_vector_type(8))) short bf16x8;

__device__ __forceinline__ short f2bf(float f) {
    union { float f; unsigned u; } v; v.f = f;
    unsigned r = v.u + 0x7fff + ((v.u >> 16) & 1);
    return (short)(r >> 16);
}
#define MFMA16(a, b, c) __builtin_amdgcn_mfma_f32_16x16x32_bf16(a, b, c, 0, 0, 0)

// ---------------------------------------------------------------- K1: logits
// logits[l][h][k] = (LN(0.5*(src[k,l,:]+src[l,k,:])) @ Wp + bp)[h]; symmetric in (k,l)
// At HBM roofline (302 MB src read) — do not touch.
__global__ __launch_bounds__(256) void k1_logits(
    const float* __restrict__ src, const float* __restrict__ Wp,
    const float* __restrict__ bp, const float* __restrict__ g_norm,
    const float* __restrict__ bt_norm, float* __restrict__ logits)
{
    int k = blockIdx.x;
    int wave = threadIdx.x >> 6;
    int lane = threadIdx.x & 63;
    int l = blockIdx.y * 4 + wave;
    if (k > l) return;
    const float* r1 = src + ((size_t)k * LL + l) * DIN;
    const float* r2 = src + ((size_t)l * LL + k) * DIN;
    float2 a = *(const float2*)(r1 + lane * 2);
    float2 b = *(const float2*)(r2 + lane * 2);
    float x0 = 0.5f * (a.x + b.x);
    float x1 = 0.5f * (a.y + b.y);
    float s = x0 + x1, ss = x0 * x0 + x1 * x1;
    #pragma unroll
    for (int m = 1; m < 64; m <<= 1) { s += __shfl_xor(s, m); ss += __shfl_xor(ss, m); }
    float mean = s * (1.0f / DIN);
    float var  = ss * (1.0f / DIN) - mean * mean;
    float rstd = rsqrtf(var + EPS);
    int d0 = lane * 2;
    float n0 = g_norm[d0]     * (x0 - mean) * rstd + bt_norm[d0];
    float n1 = g_norm[d0 + 1] * (x1 - mean) * rstd + bt_norm[d0 + 1];
    float4 w0 = *(const float4*)(Wp + d0 * HH);
    float4 w1 = *(const float4*)(Wp + d0 * HH + HH);
    float p0 = n0 * w0.x + n1 * w1.x;
    float p1 = n0 * w0.y + n1 * w1.y;
    float p2 = n0 * w0.z + n1 * w1.z;
    float p3 = n0 * w0.w + n1 * w1.w;
    #pragma unroll
    for (int m = 1; m < 64; m <<= 1) {
        p0 += __shfl_xor(p0, m); p1 += __shfl_xor(p1, m);
        p2 += __shfl_xor(p2, m); p3 += __shfl_xor(p3, m);
    }
    int hh = lane & 3;
    float pv = (hh == 0 ? p0 : hh == 1 ? p1 : hh == 2 ? p2 : p3) + bp[hh];
    if (lane < 4)                 logits[((size_t)l * HH + hh) * LL + k] = pv;
    else if (lane < 8 && k != l)  logits[((size_t)k * HH + hh) * LL + l] = pv;
}

// ---------------------------------------------------------------- K2: softmax over k, bf16 out [h][l][k]
__global__ __launch_bounds__(256) void k2_softmax(
    const float* __restrict__ logits, short* __restrict__ attn_bf)
{
    int l = blockIdx.x;
    int h = threadIdx.x >> 6;
    int lane = threadIdx.x & 63;
    const float* row = logits + ((size_t)l * HH + h) * LL;
    float v[6];
    float mx = -1e30f;
    #pragma unroll
    for (int j = 0; j < 6; j++) { v[j] = row[lane + 64 * j]; mx = fmaxf(mx, v[j]); }
    #pragma unroll
    for (int m = 1; m < 64; m <<= 1) mx = fmaxf(mx, __shfl_xor(mx, m));
    float sum = 0.f;
    #pragma unroll
    for (int j = 0; j < 6; j++) { v[j] = __expf(v[j] - mx); sum += v[j]; }
    #pragma unroll
    for (int m = 1; m < 64; m <<= 1) sum += __shfl_xor(sum, m);
    float inv = 1.0f / sum;
    short* orow = attn_bf + ((size_t)h * LL + l) * LL;
    #pragma unroll
    for (int j = 0; j < 6; j++) orow[lane + 64 * j] = f2bf(v[j] * inv);
}

// ---------------------------------------------------------------- K3: v = LN(tgt)@Wm+bm -> bf16 [h][k][n*16+c]
// MFMA: one 16-row x 64-col tile per wave per iteration; Wm frags register-resident.
__global__ __launch_bounds__(256) void k3_v(
    const float* __restrict__ tgt, const float* __restrict__ Wm,
    const float* __restrict__ bm, const float* __restrict__ g1,
    const float* __restrict__ bt1, short* __restrict__ vt_bf)
{
    int tid = threadIdx.x, wave = tid >> 6, lane = tid & 63;
    int c15 = lane & 15, g = lane >> 4;
    bf16x8 wb[2][4];
    #pragma unroll
    for (int kf = 0; kf < 2; kf++)
        #pragma unroll
        for (int nt = 0; nt < 4; nt++) {
            bf16x8 w;
            #pragma unroll
            for (int i = 0; i < 8; i++) {
                int k = kf * 32 + g * 8 + i;
                w[i] = f2bf(Wm[k * DOUT + c15 * HH + nt]);
            }
            wb[kf][nt] = w;
        }
    float bmr[4];
    #pragma unroll
    for (int nt = 0; nt < 4; nt++) bmr[nt] = bm[c15 * HH + nt];
    float g1a[8], g1b[8], bta[8], btb[8];
    #pragma unroll
    for (int i = 0; i < 8; i++) {
        g1a[i] = g1[g * 8 + i];       bta[i] = bt1[g * 8 + i];
        g1b[i] = g1[32 + g * 8 + i];  btb[i] = bt1[32 + g * 8 + i];
    }
    const f32x4 zero = {0.f, 0.f, 0.f, 0.f};
    int gwave = blockIdx.x * 4 + wave;
    int nwaves = gridDim.x * 4;
    const int NT = NN * LL / 16;
    for (int t = gwave; t < NT; t += nwaves) {
        int r0 = t * 16;
        const float* tb = tgt + (size_t)r0 * DOUT + c15 * DOUT + g * 8;
        float4 xa = *(const float4*)(tb);
        float4 xb = *(const float4*)(tb + 4);
        float4 xc = *(const float4*)(tb + 32);
        float4 xd = *(const float4*)(tb + 36);
        float ya[8] = {xa.x, xa.y, xa.z, xa.w, xb.x, xb.y, xb.z, xb.w};
        float yb[8] = {xc.x, xc.y, xc.z, xc.w, xd.x, xd.y, xd.z, xd.w};
        float s = 0.f, ss = 0.f;
        #pragma unroll
        for (int i = 0; i < 8; i++) {
            s += ya[i] + yb[i];
            ss += ya[i] * ya[i] + yb[i] * yb[i];
        }
        s  += __shfl_xor(s, 16);  s  += __shfl_xor(s, 32);
        ss += __shfl_xor(ss, 16); ss += __shfl_xor(ss, 32);
        float mean = s * (1.0f / DOUT);
        float var  = ss * (1.0f / DOUT) - mean * mean;
        float rstd = rsqrtf(var + EPS);
        bf16x8 a0, a1;
        #pragma unroll
        for (int i = 0; i < 8; i++) {
            a0[i] = f2bf(g1a[i] * (ya[i] - mean) * rstd + bta[i]);
            a1[i] = f2bf(g1b[i] * (yb[i] - mean) * rstd + btb[i]);
        }
        f32x4 acc[4];
        #pragma unroll
        for (int nt = 0; nt < 4; nt++) {
            acc[nt] = MFMA16(a0, wb[0][nt], zero);
            acc[nt] = MFMA16(a1, wb[1][nt], acc[nt]);
        }
        int n = r0 / LL, k0 = r0 % LL;
        #pragma unroll
        for (int nt = 0; nt < 4; nt++)
            #pragma unroll
            for (int j = 0; j < 4; j++) {
                int k = k0 + g * 4 + j;
                vt_bf[((size_t)(nt * LL + k)) * (NN * CC) + n * CC + c15] =
                    f2bf(acc[nt][j] + bmr[nt]);
            }
    }
}

// ---------------------------------------------------------------- K4: einsum via MFMA per head
// C_h[l=384][m=32-tile] = sum_k attn_bf[h][l][k] * vt_bf[h][k][m0+m]; BK=32, BM=32
// grid 1024 blocks -> 4 blocks/CU (33 KB LDS), 16 waves/CU.
#define K4S 40   // stride in shorts (80 B rows): bank = l*20 mod 32 -> 8 slots, 2-way free
__global__ __launch_bounds__(256) void k4_mfma(
    const short* __restrict__ attn_bf, const short* __restrict__ vt_bf,
    short* __restrict__ o_bf)
{
    __shared__ short As[LL * K4S];   // 30720 B
    __shared__ short Bs[32 * K4S];   // 2560 B
    int h = blockIdx.y;
    int m0 = blockIdx.x * 32;
    int tid = threadIdx.x, wave = tid >> 6, lane = tid & 63;
    int c15 = lane & 15, g = lane >> 4;
    f32x4 acc[6][2];
    #pragma unroll
    for (int i = 0; i < 6; i++)
        #pragma unroll
        for (int nt = 0; nt < 2; nt++) acc[i][nt] = (f32x4){0.f, 0.f, 0.f, 0.f};

    for (int k0 = 0; k0 < LL; k0 += 32) {
        __syncthreads();
        // stage A: 384 l x 32 k bf16, 16B vector copies
        #pragma unroll
        for (int it = 0; it < 6; it++) {
            int e = tid + 256 * it;           // 0..1535
            int l = e >> 2, k8 = (e & 3) * 8;
            bf16x8 v = *(const bf16x8*)(attn_bf + ((size_t)(h * LL + l)) * LL + k0 + k8);
            *(bf16x8*)(As + l * K4S + k8) = v;
        }
        // stage B transposed: Bs[m][kk] = vt[h][k0+kk][m0+m]; m=tid&31, 4 k per thread
        {
            int m = tid & 31, kg = tid >> 5;   // kg 0..7
            const short* vb = vt_bf + ((size_t)(h * LL + k0 + kg * 4)) * (NN * CC) + m0 + m;
            short tmp[4];
            #pragma unroll
            for (int j = 0; j < 4; j++) tmp[j] = vb[(size_t)j * (NN * CC)];
            #pragma unroll
            for (int j = 0; j < 2; j++) {
                int v2 = (int)(unsigned short)tmp[2 * j] | ((int)(unsigned short)tmp[2 * j + 1] << 16);
                *(int*)(Bs + m * K4S + kg * 4 + 2 * j) = v2;
            }
        }
        __syncthreads();
        bf16x8 bfr[2];
        #pragma unroll
        for (int nt = 0; nt < 2; nt++)
            bfr[nt] = *(const bf16x8*)(Bs + (nt * 16 + c15) * K4S + g * 8);
        #pragma unroll
        for (int i = 0; i < 6; i++) {
            int l = (wave + 4 * i) * 16 + c15;
            bf16x8 afr = *(const bf16x8*)(As + l * K4S + g * 8);
            #pragma unroll
            for (int nt = 0; nt < 2; nt++)
                acc[i][nt] = MFMA16(afr, bfr[nt], acc[i][nt]);
        }
    }
    // epilogue: o_bf[(n*LL+l)][h*16+c]
    #pragma unroll
    for (int i = 0; i < 6; i++) {
        int l = (wave + 4 * i) * 16 + g * 4;
        #pragma unroll
        for (int nt = 0; nt < 2; nt++) {
            int n = (m0 >> 4) + nt;
            #pragma unroll
            for (int r = 0; r < 4; r++)
                o_bf[((size_t)n * LL + l + r) * DOUT + h * 16 + c15] = f2bf(acc[i][nt][r]);
        }
    }
}

// ---------------------------------------------------------------- K5: fused tail (Wo+res+LN+FFN+res), MFMA
// XOR-swizzled flat-stride LDS (128 KB): sidx = row*S + (col ^ ((row&7)<<3))
// per-wave 16-row tiles, next-tile global prefetch into registers.
#define SWZ(col, row) ((col) ^ (((row) & 7) << 3))
#define K5_LDS ((DFF * 64 + DOUT * 256 + 8 * 16 * 256) * 2)   // 131072 B
__global__ __launch_bounds__(512) void k5_tail(
    const short* __restrict__ o_bf, const float* __restrict__ tgt,
    const float* __restrict__ Wo, const float* __restrict__ bo,
    const float* __restrict__ W1, const float* __restrict__ b1,
    const float* __restrict__ W2, const float* __restrict__ b2,
    const float* __restrict__ g2, const float* __restrict__ bt2,
    float* __restrict__ out)
{
    extern __shared__ short smem[];
    short* W1T = smem;                       // [p=ff 0..255][k=d 0..63] swizzled
    short* W2T = W1T + DFF * 64;             // [n=d 0..63][k=ff 0..255] swizzled
    short* Fl  = W2T + DOUT * 256;           // per-wave [16][256] swizzled
    int tid = threadIdx.x, wave = tid >> 6, lane = tid & 63;
    int c15 = lane & 15, g = lane >> 4;

    // stage transposed weights (once per block), swizzled scalar writes
    for (int e = tid; e < DOUT * DFF; e += 512) {
        int k = e >> 8, p = e & 255;
        W1T[p * 64 + SWZ(k, p)] = f2bf(W1[e]);        // W1[k*DFF+p]
        int k2 = e >> 6, n = e & 63;
        W2T[n * 256 + SWZ(k2, n)] = f2bf(W2[e]);      // W2[k2*DOUT+n]
    }
    // preload Wo B-frags (rows permuted: o cols are h*16+c <-> Wo row c*4+h)
    bf16x8 woB[2][4];
    #pragma unroll
    for (int kf = 0; kf < 2; kf++)
        #pragma unroll
        for (int nt = 0; nt < 4; nt++) {
            bf16x8 w;
            #pragma unroll
            for (int i2 = 0; i2 < 8; i2++) {
                int k = kf * 32 + g * 8 + i2;
                int rj = (k & 15) * 4 + (k >> 4);
                w[i2] = f2bf(Wo[rj * DOUT + nt * 16 + c15]);
            }
            woB[kf][nt] = w;
        }
    float bor[4], b2r[4], g2r[4], bt2r[4], b1r[16];
    #pragma unroll
    for (int nt = 0; nt < 4; nt++) {
        bor[nt]  = bo[nt * 16 + c15];  b2r[nt]  = b2[nt * 16 + c15];
        g2r[nt]  = g2[nt * 16 + c15];  bt2r[nt] = bt2[nt * 16 + c15];
    }
    #pragma unroll
    for (int nt = 0; nt < 16; nt++) b1r[nt] = b1[nt * 16 + c15];
    __syncthreads();

    short* Fw = Fl + wave * 16 * 256;
    int gwave = blockIdx.x * 8 + wave;
    const f32x4 zero = {0.f, 0.f, 0.f, 0.f};

    // prefetch tile 0 inputs
    int r0c = (gwave * 6) * 16;
    bf16x8 oa0 = *(const bf16x8*)(o_bf + (size_t)r0c * DOUT + c15 * DOUT + g * 8);
    bf16x8 oa1 = *(const bf16x8*)(o_bf + (size_t)r0c * DOUT + c15 * DOUT + 32 + g * 8);
    float tg[16];
    #pragma unroll
    for (int nt = 0; nt < 4; nt++)
        #pragma unroll
        for (int j = 0; j < 4; j++)
            tg[nt * 4 + j] = tgt[(size_t)r0c * DOUT + (g * 4 + j) * DOUT + nt * 16 + c15];

    for (int it = 0; it < 6; it++) {
        int r0 = r0c;
        // issue next-tile loads (hide HBM latency under this tile's MFMAs)
        int r0n = (it < 5) ? (gwave * 6 + it + 1) * 16 : r0c;
        bf16x8 noa0 = *(const bf16x8*)(o_bf + (size_t)r0n * DOUT + c15 * DOUT + g * 8);
        bf16x8 noa1 = *(const bf16x8*)(o_bf + (size_t)r0n * DOUT + c15 * DOUT + 32 + g * 8);
        float ntg[16];
        #pragma unroll
        for (int nt = 0; nt < 4; nt++)
            #pragma unroll
            for (int j = 0; j < 4; j++)
                ntg[nt * 4 + j] = tgt[(size_t)r0n * DOUT + (g * 4 + j) * DOUT + nt * 16 + c15];

        // ---- stage1: X = tgt + o@Wo + bo
        f32x4 X[4];
        #pragma unroll
        for (int nt = 0; nt < 4; nt++) {
            X[nt] = MFMA16(oa0, woB[0][nt], zero);
            X[nt] = MFMA16(oa1, woB[1][nt], X[nt]);
        }
        #pragma unroll
        for (int nt = 0; nt < 4; nt++)
            #pragma unroll
            for (int j = 0; j < 4; j++)
                X[nt][j] += tg[nt * 4 + j] + bor[nt];
        // ---- stage2: LN over d
        #pragma unroll
        for (int j = 0; j < 4; j++) {
            float s  = X[0][j] + X[1][j] + X[2][j] + X[3][j];
            float ss = X[0][j]*X[0][j] + X[1][j]*X[1][j] + X[2][j]*X[2][j] + X[3][j]*X[3][j];
            #pragma unroll
            for (int m = 1; m < 16; m <<= 1) { s += __shfl_xor(s, m); ss += __shfl_xor(ss, m); }
            float mean = s * (1.0f / DOUT);
            float var  = ss * (1.0f / DOUT) - mean * mean;
            float rstd = rsqrtf(var + EPS);
            int row = g * 4 + j;
            #pragma unroll
            for (int nt = 0; nt < 4; nt++) {
                float y = g2r[nt] * (X[nt][j] - mean) * rstd + bt2r[nt];
                Fw[row * 256 + SWZ(nt * 16 + c15, row)] = f2bf(y);
            }
        }
        // ---- stage3: F = relu(Y@W1 + b1)
        bf16x8 ya0 = *(const bf16x8*)(Fw + c15 * 256 + SWZ(g * 8, c15));
        bf16x8 ya1 = *(const bf16x8*)(Fw + c15 * 256 + SWZ(32 + g * 8, c15));
        f32x4 Fa[16];
        #pragma unroll
        for (int nt = 0; nt < 16; nt++) {
            int row = nt * 16 + c15;
            bf16x8 wb0 = *(const bf16x8*)(W1T + row * 64 + SWZ(g * 8, row));
            bf16x8 wb1 = *(const bf16x8*)(W1T + row * 64 + SWZ(32 + g * 8, row));
            Fa[nt] = MFMA16(ya0, wb0, zero);
            Fa[nt] = MFMA16(ya1, wb1, Fa[nt]);
        }
        #pragma unroll
        for (int nt = 0; nt < 16; nt++)
            #pragma unroll
            for (int j = 0; j < 4; j++) {
                int row = g * 4 + j;
                Fw[row * 256 + SWZ(nt * 16 + c15, row)] = f2bf(fmaxf(Fa[nt][j] + b1r[nt], 0.f));
            }
        // ---- stage4: out = X + F@W2 + b2
        bf16x8 fa[8];
        #pragma unroll
        for (int kf = 0; kf < 8; kf++)
            fa[kf] = *(const bf16x8*)(Fw + c15 * 256 + SWZ(kf * 32 + g * 8, c15));
        #pragma unroll
        for (int nt = 0; nt < 4; nt++)
            #pragma unroll
            for (int kf = 0; kf < 8; kf++) {
                int row = nt * 16 + c15;
                bf16x8 wb = *(const bf16x8*)(W2T + row * 256 + SWZ(kf * 32 + g * 8, row));
                X[nt] = MFMA16(fa[kf], wb, X[nt]);
            }
        float* outb = out + (size_t)r0 * DOUT;
        #pragma unroll
        for (int nt = 0; nt < 4; nt++)
            #pragma unroll
            for (int j = 0; j < 4; j++)
                outb[(g * 4 + j) * DOUT + nt * 16 + c15] = X[nt][j] + b2r[nt];

        // rotate prefetched inputs
        oa0 = noa0; oa1 = noa1;
        #pragma unroll
        for (int q = 0; q < 16; q++) tg[q] = ntg[q];
        r0c = r0n;
    }
}

// ---------------------------------------------------------------- launch
extern "C" void kernel_launch(void* const* d_in, const int* in_sizes, int n_in,
                              void* d_out, int out_size, void* d_ws, size_t ws_size,
                              hipStream_t stream)
{
    (void)in_sizes; (void)n_in; (void)out_size; (void)ws_size;
    const float* src     = (const float*)d_in[0];
    const float* tgt     = (const float*)d_in[1];
    const float* Wp      = (const float*)d_in[2];
    const float* bp      = (const float*)d_in[3];
    const float* Wm      = (const float*)d_in[4];
    const float* bm      = (const float*)d_in[5];
    const float* Wo      = (const float*)d_in[6];
    const float* bo      = (const float*)d_in[7];
    const float* W1      = (const float*)d_in[8];
    const float* b1      = (const float*)d_in[9];
    const float* W2      = (const float*)d_in[10];
    const float* b2      = (const float*)d_in[11];
    const float* g_norm  = (const float*)d_in[12];
    const float* bt_norm = (const float*)d_in[13];
    const float* g1      = (const float*)d_in[14];
    const float* bt1     = (const float*)d_in[15];
    const float* g2      = (const float*)d_in[16];
    const float* bt2     = (const float*)d_in[17];
    float* out = (float*)d_out;
    float* ws  = (float*)d_ws;

    float* logits  = ws;                                  // 589824 f32
    short* attn_bf = (short*)(ws + 589824);               // [h][l][k] 589824 bf16
    short* vt_bf   = attn_bf + 589824;                    // [h][k][n*16+c] 12582912 bf16
    short* o_bf    = vt_bf + 12582912;                    // [n*384+l][h*16+c] 12582912 bf16

    hipFuncSetAttribute((const void*)k5_tail,
                        hipFuncAttributeMaxDynamicSharedMemorySize, K5_LDS);

    k1_logits <<<dim3(LL, LL / 4), 256, 0, stream>>>(src, Wp, bp, g_norm, bt_norm, logits);
    k2_softmax<<<LL, 256, 0, stream>>>(logits, attn_bf);
    k3_v      <<<1024, 256, 0, stream>>>(tgt, Wm, bm, g1, bt1, vt_bf);
    k4_mfma   <<<dim3((NN * CC) / 32, HH), 256, 0, stream>>>(attn_bf, vt_bf, o_bf);
    k5_tail   <<<256, 512, K5_LDS, stream>>>(o_bf, tgt, Wo, bo, W1, b1, W2, b2, g2, bt2, out);
}

// Round 6
// 300.696 us; speedup vs baseline: 1.0498x; 1.0498x over previous
//
#include <hip/hip_runtime.h>
#include <math.h>

#define LL 384
#define NN 512
#define DIN 128
#define DOUT 64
#define HH 4
#define CC 16
#define DFF 256
#define EPS 1e-5f

typedef __attribute__((ext_vector_type(4))) float f32x4;
typedef __attribute__((ext_vector_type(8))) short bf16x8;

__device__ __forceinline__ short f2bf(float f) {
    union { float f; unsigned u; } v; v.f = f;
    unsigned r = v.u + 0x7fff + ((v.u >> 16) & 1);
    return (short)(r >> 16);
}
#define MFMA16(a, b, c) __builtin_amdgcn_mfma_f32_16x16x32_bf16(a, b, c, 0, 0, 0)

// ---------------------------------------------------------------- K1: logits
// logits[l][h][k] = (LN(0.5*(src[k,l,:]+src[l,k,:])) @ Wp + bp)[h]; symmetric in (k,l)
// At HBM roofline (302 MB src read) — do not touch.
__global__ __launch_bounds__(256) void k1_logits(
    const float* __restrict__ src, const float* __restrict__ Wp,
    const float* __restrict__ bp, const float* __restrict__ g_norm,
    const float* __restrict__ bt_norm, float* __restrict__ logits)
{
    int k = blockIdx.x;
    int wave = threadIdx.x >> 6;
    int lane = threadIdx.x & 63;
    int l = blockIdx.y * 4 + wave;
    if (k > l) return;
    const float* r1 = src + ((size_t)k * LL + l) * DIN;
    const float* r2 = src + ((size_t)l * LL + k) * DIN;
    float2 a = *(const float2*)(r1 + lane * 2);
    float2 b = *(const float2*)(r2 + lane * 2);
    float x0 = 0.5f * (a.x + b.x);
    float x1 = 0.5f * (a.y + b.y);
    float s = x0 + x1, ss = x0 * x0 + x1 * x1;
    #pragma unroll
    for (int m = 1; m < 64; m <<= 1) { s += __shfl_xor(s, m); ss += __shfl_xor(ss, m); }
    float mean = s * (1.0f / DIN);
    float var  = ss * (1.0f / DIN) - mean * mean;
    float rstd = rsqrtf(var + EPS);
    int d0 = lane * 2;
    float n0 = g_norm[d0]     * (x0 - mean) * rstd + bt_norm[d0];
    float n1 = g_norm[d0 + 1] * (x1 - mean) * rstd + bt_norm[d0 + 1];
    float4 w0 = *(const float4*)(Wp + d0 * HH);
    float4 w1 = *(const float4*)(Wp + d0 * HH + HH);
    float p0 = n0 * w0.x + n1 * w1.x;
    float p1 = n0 * w0.y + n1 * w1.y;
    float p2 = n0 * w0.z + n1 * w1.z;
    float p3 = n0 * w0.w + n1 * w1.w;
    #pragma unroll
    for (int m = 1; m < 64; m <<= 1) {
        p0 += __shfl_xor(p0, m); p1 += __shfl_xor(p1, m);
        p2 += __shfl_xor(p2, m); p3 += __shfl_xor(p3, m);
    }
    int hh = lane & 3;
    float pv = (hh == 0 ? p0 : hh == 1 ? p1 : hh == 2 ? p2 : p3) + bp[hh];
    if (lane < 4)                 logits[((size_t)l * HH + hh) * LL + k] = pv;
    else if (lane < 8 && k != l)  logits[((size_t)k * HH + hh) * LL + l] = pv;
}

// ---------------------------------------------------------------- K2: softmax over k, bf16 out [h][l][k]
__global__ __launch_bounds__(256) void k2_softmax(
    const float* __restrict__ logits, short* __restrict__ attn_bf)
{
    int l = blockIdx.x;
    int h = threadIdx.x >> 6;
    int lane = threadIdx.x & 63;
    const float* row = logits + ((size_t)l * HH + h) * LL;
    float v[6];
    float mx = -1e30f;
    #pragma unroll
    for (int j = 0; j < 6; j++) { v[j] = row[lane + 64 * j]; mx = fmaxf(mx, v[j]); }
    #pragma unroll
    for (int m = 1; m < 64; m <<= 1) mx = fmaxf(mx, __shfl_xor(mx, m));
    float sum = 0.f;
    #pragma unroll
    for (int j = 0; j < 6; j++) { v[j] = __expf(v[j] - mx); sum += v[j]; }
    #pragma unroll
    for (int m = 1; m < 64; m <<= 1) sum += __shfl_xor(sum, m);
    float inv = 1.0f / sum;
    short* orow = attn_bf + ((size_t)h * LL + l) * LL;
    #pragma unroll
    for (int j = 0; j < 6; j++) orow[lane + 64 * j] = f2bf(v[j] * inv);
}

// ---------------------------------------------------------------- K3: v = LN(tgt)@Wm+bm -> bf16 [h][k][n*16+c]
// MFMA: one 16-row x 64-col tile per wave per iteration; Wm frags register-resident.
__global__ __launch_bounds__(256) void k3_v(
    const float* __restrict__ tgt, const float* __restrict__ Wm,
    const float* __restrict__ bm, const float* __restrict__ g1,
    const float* __restrict__ bt1, short* __restrict__ vt_bf)
{
    int tid = threadIdx.x, wave = tid >> 6, lane = tid & 63;
    int c15 = lane & 15, g = lane >> 4;
    bf16x8 wb[2][4];
    #pragma unroll
    for (int kf = 0; kf < 2; kf++)
        #pragma unroll
        for (int nt = 0; nt < 4; nt++) {
            bf16x8 w;
            #pragma unroll
            for (int i = 0; i < 8; i++) {
                int k = kf * 32 + g * 8 + i;
                w[i] = f2bf(Wm[k * DOUT + c15 * HH + nt]);
            }
            wb[kf][nt] = w;
        }
    float bmr[4];
    #pragma unroll
    for (int nt = 0; nt < 4; nt++) bmr[nt] = bm[c15 * HH + nt];
    float g1a[8], g1b[8], bta[8], btb[8];
    #pragma unroll
    for (int i = 0; i < 8; i++) {
        g1a[i] = g1[g * 8 + i];       bta[i] = bt1[g * 8 + i];
        g1b[i] = g1[32 + g * 8 + i];  btb[i] = bt1[32 + g * 8 + i];
    }
    const f32x4 zero = {0.f, 0.f, 0.f, 0.f};
    int gwave = blockIdx.x * 4 + wave;
    int nwaves = gridDim.x * 4;
    const int NT = NN * LL / 16;
    for (int t = gwave; t < NT; t += nwaves) {
        int r0 = t * 16;
        const float* tb = tgt + (size_t)r0 * DOUT + c15 * DOUT + g * 8;
        float4 xa = *(const float4*)(tb);
        float4 xb = *(const float4*)(tb + 4);
        float4 xc = *(const float4*)(tb + 32);
        float4 xd = *(const float4*)(tb + 36);
        float ya[8] = {xa.x, xa.y, xa.z, xa.w, xb.x, xb.y, xb.z, xb.w};
        float yb[8] = {xc.x, xc.y, xc.z, xc.w, xd.x, xd.y, xd.z, xd.w};
        float s = 0.f, ss = 0.f;
        #pragma unroll
        for (int i = 0; i < 8; i++) {
            s += ya[i] + yb[i];
            ss += ya[i] * ya[i] + yb[i] * yb[i];
        }
        s  += __shfl_xor(s, 16);  s  += __shfl_xor(s, 32);
        ss += __shfl_xor(ss, 16); ss += __shfl_xor(ss, 32);
        float mean = s * (1.0f / DOUT);
        float var  = ss * (1.0f / DOUT) - mean * mean;
        float rstd = rsqrtf(var + EPS);
        bf16x8 a0, a1;
        #pragma unroll
        for (int i = 0; i < 8; i++) {
            a0[i] = f2bf(g1a[i] * (ya[i] - mean) * rstd + bta[i]);
            a1[i] = f2bf(g1b[i] * (yb[i] - mean) * rstd + btb[i]);
        }
        f32x4 acc[4];
        #pragma unroll
        for (int nt = 0; nt < 4; nt++) {
            acc[nt] = MFMA16(a0, wb[0][nt], zero);
            acc[nt] = MFMA16(a1, wb[1][nt], acc[nt]);
        }
        int n = r0 / LL, k0 = r0 % LL;
        #pragma unroll
        for (int nt = 0; nt < 4; nt++)
            #pragma unroll
            for (int j = 0; j < 4; j++) {
                int k = k0 + g * 4 + j;
                vt_bf[((size_t)(nt * LL + k)) * (NN * CC) + n * CC + c15] =
                    f2bf(acc[nt][j] + bmr[nt]);
            }
    }
}

// ---------------------------------------------------------------- K4: einsum via MFMA per head (round-3 proven config)
// C_h[l=384][m=64-tile] = sum_k attn_bf[h][l][k] * vt_bf[h][k][m0+m]; BK=32
#define K4S 56   // LDS row stride in elems (112 B: 16B-aligned, 8 distinct bank starts)
__global__ __launch_bounds__(256) void k4_mfma(
    const short* __restrict__ attn_bf, const short* __restrict__ vt_bf,
    short* __restrict__ o_bf)
{
    __shared__ short As[LL * K4S];   // 43008 B
    __shared__ short Bs[64 * K4S];   // 7168 B
    int h = blockIdx.y;
    int m0 = blockIdx.x * 64;
    int tid = threadIdx.x, wave = tid >> 6, lane = tid & 63;
    int c15 = lane & 15, g = lane >> 4;
    f32x4 acc[6][4];
    #pragma unroll
    for (int i = 0; i < 6; i++)
        #pragma unroll
        for (int nt = 0; nt < 4; nt++) acc[i][nt] = (f32x4){0.f, 0.f, 0.f, 0.f};

    for (int k0 = 0; k0 < LL; k0 += 32) {
        __syncthreads();
        #pragma unroll
        for (int it = 0; it < 6; it++) {
            int e = tid + 256 * it;           // 0..1535
            int l = e >> 2, k8 = (e & 3) * 8;
            bf16x8 v = *(const bf16x8*)(attn_bf + ((size_t)(h * LL + l)) * LL + k0 + k8);
            *(bf16x8*)(As + l * K4S + k8) = v;
        }
        {
            int m = tid & 63, kg = tid >> 6;
            const short* vb = vt_bf + ((size_t)(h * LL + k0 + kg * 8)) * (NN * CC) + m0 + m;
            short tmp[8];
            #pragma unroll
            for (int j = 0; j < 8; j++) tmp[j] = vb[(size_t)j * (NN * CC)];
            #pragma unroll
            for (int j = 0; j < 4; j++) {
                int v2 = (int)(unsigned short)tmp[2 * j] | ((int)(unsigned short)tmp[2 * j + 1] << 16);
                *(int*)(Bs + m * K4S + kg * 8 + 2 * j) = v2;
            }
        }
        __syncthreads();
        bf16x8 bfr[4];
        #pragma unroll
        for (int nt = 0; nt < 4; nt++)
            bfr[nt] = *(const bf16x8*)(Bs + (nt * 16 + c15) * K4S + g * 8);
        #pragma unroll
        for (int i = 0; i < 6; i++) {
            int l = (wave + 4 * i) * 16 + c15;
            bf16x8 afr = *(const bf16x8*)(As + l * K4S + g * 8);
            #pragma unroll
            for (int nt = 0; nt < 4; nt++)
                acc[i][nt] = MFMA16(afr, bfr[nt], acc[i][nt]);
        }
    }
    #pragma unroll
    for (int i = 0; i < 6; i++) {
        int l = (wave + 4 * i) * 16 + g * 4;
        #pragma unroll
        for (int nt = 0; nt < 4; nt++) {
            int n = (m0 >> 4) + nt;
            #pragma unroll
            for (int r = 0; r < 4; r++)
                o_bf[((size_t)n * LL + l + r) * DOUT + h * 16 + c15] = f2bf(acc[i][nt][r]);
        }
    }
}

// ---------------------------------------------------------------- K5: fused tail (Wo+res+LN+FFN+res), MFMA
// 32 rows/iter (2 halves share every weight B-frag read), F in 128-col chunks,
// granule-XOR swizzle col ^= ((row>>2)&3)<<4 kills scalar-write bank conflicts
// (rows 4-apart land on 4 distinct granules; b128 reads stay bijective+aligned).
#define SW(col, row) ((col) ^ ((((row) >> 2) & 3) << 4))
#define W1TS 72
#define W2TS 264
#define FS 136
#define K5_LDS ((DFF * W1TS + DOUT * W2TS + 8 * 32 * FS) * 2)   // 140288 B
__global__ __launch_bounds__(512, 2) void k5_tail(
    const short* __restrict__ o_bf, const float* __restrict__ tgt,
    const float* __restrict__ Wo, const float* __restrict__ bo,
    const float* __restrict__ W1, const float* __restrict__ b1,
    const float* __restrict__ W2, const float* __restrict__ b2,
    const float* __restrict__ g2, const float* __restrict__ bt2,
    float* __restrict__ out)
{
    extern __shared__ short smem[];
    short* W1T = smem;                       // [p=ff][k=d 0..63], stride 72, swizzled
    short* W2T = W1T + DFF * W1TS;           // [n=d][k=ff 0..255], stride 264, swizzled
    short* Fl  = W2T + DOUT * W2TS;          // per-wave [32][FS], swizzled
    int tid = threadIdx.x, wave = tid >> 6, lane = tid & 63;
    int c15 = lane & 15, g = lane >> 4;

    for (int e = tid; e < DOUT * DFF; e += 512) {
        int k = e >> 8, p = e & 255;
        W1T[p * W1TS + SW(k, p)] = f2bf(W1[e]);        // W1[k*DFF+p]
        int k2 = e >> 6, n = e & 63;
        W2T[n * W2TS + SW(k2, n)] = f2bf(W2[e]);       // W2[k2*DOUT+n]
    }
    // Wo B-frags (rows permuted: o cols are h*16+c <-> Wo row c*4+h)
    bf16x8 woB[2][4];
    #pragma unroll
    for (int kf = 0; kf < 2; kf++)
        #pragma unroll
        for (int nt = 0; nt < 4; nt++) {
            bf16x8 w;
            #pragma unroll
            for (int i2 = 0; i2 < 8; i2++) {
                int k = kf * 32 + g * 8 + i2;
                int rj = (k & 15) * 4 + (k >> 4);
                w[i2] = f2bf(Wo[rj * DOUT + nt * 16 + c15]);
            }
            woB[kf][nt] = w;
        }
    float bor[4], b2r[4], g2r[4], bt2r[4], b1r[16];
    #pragma unroll
    for (int nt = 0; nt < 4; nt++) {
        bor[nt]  = bo[nt * 16 + c15];  b2r[nt]  = b2[nt * 16 + c15];
        g2r[nt]  = g2[nt * 16 + c15];  bt2r[nt] = bt2[nt * 16 + c15];
    }
    #pragma unroll
    for (int pt = 0; pt < 16; pt++) b1r[pt] = b1[pt * 16 + c15];
    __syncthreads();

    short* Fw = Fl + wave * 32 * FS;
    int gwave = blockIdx.x * 8 + wave;
    const f32x4 zero = {0.f, 0.f, 0.f, 0.f};

    for (int it = 0; it < 3; it++) {
        int r0 = (gwave * 3 + it) * 32;
        // ---- stage1: X = tgt + o@Wo + bo, two 16-row halves
        f32x4 X[2][4];
        #pragma unroll
        for (int h = 0; h < 2; h++) {
            const short* ob = o_bf + ((size_t)(r0 + h * 16) + c15) * DOUT;
            bf16x8 oa0 = *(const bf16x8*)(ob + g * 8);
            bf16x8 oa1 = *(const bf16x8*)(ob + 32 + g * 8);
            #pragma unroll
            for (int nt = 0; nt < 4; nt++) {
                X[h][nt] = MFMA16(oa0, woB[0][nt], zero);
                X[h][nt] = MFMA16(oa1, woB[1][nt], X[h][nt]);
            }
            const float* tb = tgt + (size_t)(r0 + h * 16) * DOUT;
            #pragma unroll
            for (int nt = 0; nt < 4; nt++)
                #pragma unroll
                for (int j = 0; j < 4; j++)
                    X[h][nt][j] += tb[(g * 4 + j) * DOUT + nt * 16 + c15] + bor[nt];
        }
        // ---- stage2: LN over d, write Y into Fw rows [h*16+g*4+j], cols 0..63
        #pragma unroll
        for (int h = 0; h < 2; h++)
            #pragma unroll
            for (int j = 0; j < 4; j++) {
                float s  = X[h][0][j] + X[h][1][j] + X[h][2][j] + X[h][3][j];
                float ss = X[h][0][j]*X[h][0][j] + X[h][1][j]*X[h][1][j]
                         + X[h][2][j]*X[h][2][j] + X[h][3][j]*X[h][3][j];
                #pragma unroll
                for (int m = 1; m < 16; m <<= 1) { s += __shfl_xor(s, m); ss += __shfl_xor(ss, m); }
                float mean = s * (1.0f / DOUT);
                float var  = ss * (1.0f / DOUT) - mean * mean;
                float rstd = rsqrtf(var + EPS);
                int row = h * 16 + g * 4 + j;
                #pragma unroll
                for (int nt = 0; nt < 4; nt++) {
                    float y = g2r[nt] * (X[h][nt][j] - mean) * rstd + bt2r[nt];
                    Fw[row * FS + SW(nt * 16 + c15, row)] = f2bf(y);
                }
            }
        // ---- Y A-frags (Y dead in LDS after this; chunks may overwrite)
        bf16x8 ya0[2], ya1[2];
        #pragma unroll
        for (int h = 0; h < 2; h++) {
            int yr = h * 16 + c15;
            ya0[h] = *(const bf16x8*)(Fw + yr * FS + SW(g * 8, yr));
            ya1[h] = *(const bf16x8*)(Fw + yr * FS + SW(32 + g * 8, yr));
        }
        // ---- FFN in two 128-col chunks: F = relu(Y@W1+b1); X += F@W2
        #pragma unroll
        for (int ch = 0; ch < 2; ch++) {
            f32x4 Fa[2][8];
            #pragma unroll
            for (int nt8 = 0; nt8 < 8; nt8++) {
                int pt = ch * 8 + nt8;
                int wr = pt * 16 + c15;
                bf16x8 w0 = *(const bf16x8*)(W1T + wr * W1TS + SW(g * 8, wr));
                bf16x8 w1 = *(const bf16x8*)(W1T + wr * W1TS + SW(32 + g * 8, wr));
                #pragma unroll
                for (int h = 0; h < 2; h++) {
                    Fa[h][nt8] = MFMA16(ya0[h], w0, zero);
                    Fa[h][nt8] = MFMA16(ya1[h], w1, Fa[h][nt8]);
                }
            }
            #pragma unroll
            for (int h = 0; h < 2; h++)
                #pragma unroll
                for (int nt8 = 0; nt8 < 8; nt8++)
                    #pragma unroll
                    for (int j = 0; j < 4; j++) {
                        int row = h * 16 + g * 4 + j;
                        Fw[row * FS + SW(nt8 * 16 + c15, row)] =
                            f2bf(fmaxf(Fa[h][nt8][j] + b1r[ch * 8 + nt8], 0.f));
                    }
            bf16x8 fa[2][4];
            #pragma unroll
            for (int h = 0; h < 2; h++) {
                int fr = h * 16 + c15;
                #pragma unroll
                for (int kfl = 0; kfl < 4; kfl++)
                    fa[h][kfl] = *(const bf16x8*)(Fw + fr * FS + SW(kfl * 32 + g * 8, fr));
            }
            #pragma unroll
            for (int nt = 0; nt < 4; nt++) {
                int wr2 = nt * 16 + c15;
                #pragma unroll
                for (int kfl = 0; kfl < 4; kfl++) {
                    bf16x8 w = *(const bf16x8*)(W2T + wr2 * W2TS + SW((ch * 4 + kfl) * 32 + g * 8, wr2));
                    #pragma unroll
                    for (int h = 0; h < 2; h++)
                        X[h][nt] = MFMA16(fa[h][kfl], w, X[h][nt]);
                }
            }
        }
        // ---- store out = X + b2
        #pragma unroll
        for (int h = 0; h < 2; h++) {
            float* outb = out + (size_t)(r0 + h * 16) * DOUT;
            #pragma unroll
            for (int nt = 0; nt < 4; nt++)
                #pragma unroll
                for (int j = 0; j < 4; j++)
                    outb[(g * 4 + j) * DOUT + nt * 16 + c15] = X[h][nt][j] + b2r[nt];
        }
    }
}

// ---------------------------------------------------------------- launch
extern "C" void kernel_launch(void* const* d_in, const int* in_sizes, int n_in,
                              void* d_out, int out_size, void* d_ws, size_t ws_size,
                              hipStream_t stream)
{
    (void)in_sizes; (void)n_in; (void)out_size; (void)ws_size;
    const float* src     = (const float*)d_in[0];
    const float* tgt     = (const float*)d_in[1];
    const float* Wp      = (const float*)d_in[2];
    const float* bp      = (const float*)d_in[3];
    const float* Wm      = (const float*)d_in[4];
    const float* bm      = (const float*)d_in[5];
    const float* Wo      = (const float*)d_in[6];
    const float* bo      = (const float*)d_in[7];
    const float* W1      = (const float*)d_in[8];
    const float* b1      = (const float*)d_in[9];
    const float* W2      = (const float*)d_in[10];
    const float* b2      = (const float*)d_in[11];
    const float* g_norm  = (const float*)d_in[12];
    const float* bt_norm = (const float*)d_in[13];
    const float* g1      = (const float*)d_in[14];
    const float* bt1     = (const float*)d_in[15];
    const float* g2      = (const float*)d_in[16];
    const float* bt2     = (const float*)d_in[17];
    float* out = (float*)d_out;
    float* ws  = (float*)d_ws;

    float* logits  = ws;                                  // 589824 f32
    short* attn_bf = (short*)(ws + 589824);               // [h][l][k] 589824 bf16
    short* vt_bf   = attn_bf + 589824;                    // [h][k][n*16+c] 12582912 bf16
    short* o_bf    = vt_bf + 12582912;                    // [n*384+l][h*16+c] 12582912 bf16

    hipFuncSetAttribute((const void*)k5_tail,
                        hipFuncAttributeMaxDynamicSharedMemorySize, K5_LDS);

    k1_logits <<<dim3(LL, LL / 4), 256, 0, stream>>>(src, Wp, bp, g_norm, bt_norm, logits);
    k2_softmax<<<LL, 256, 0, stream>>>(logits, attn_bf);
    k3_v      <<<1024, 256, 0, stream>>>(tgt, Wm, bm, g1, bt1, vt_bf);
    k4_mfma   <<<dim3((NN * CC) / 64, HH), 256, 0, stream>>>(attn_bf, vt_bf, o_bf);
    k5_tail   <<<256, 512, K5_LDS, stream>>>(o_bf, tgt, Wo, bo, W1, b1, W2, b2, g2, bt2, out);
}

// Round 8
// 282.886 us; speedup vs baseline: 1.1158x; 1.0630x over previous
//
#include <hip/hip_runtime.h>
#include <math.h>

#define LL 384
#define NN 512
#define DIN 128
#define DOUT 64
#define HH 4
#define CC 16
#define DFF 256
#define EPS 1e-5f

typedef __attribute__((ext_vector_type(4))) float f32x4;
typedef __attribute__((ext_vector_type(8))) short bf16x8;

__device__ __forceinline__ short f2bf(float f) {
    union { float f; unsigned u; } v; v.f = f;
    unsigned r = v.u + 0x7fff + ((v.u >> 16) & 1);
    return (short)(r >> 16);
}
#define MFMA16(a, b, c) __builtin_amdgcn_mfma_f32_16x16x32_bf16(a, b, c, 0, 0, 0)

// ---------------------------------------------------------------- K1: logits
// logits[l][h][k] = (LN(0.5*(src[k,l,:]+src[l,k,:])) @ Wp + bp)[h]; symmetric in (k,l)
// At HBM roofline (302 MB src read) — do not touch.
__global__ __launch_bounds__(256) void k1_logits(
    const float* __restrict__ src, const float* __restrict__ Wp,
    const float* __restrict__ bp, const float* __restrict__ g_norm,
    const float* __restrict__ bt_norm, float* __restrict__ logits)
{
    int k = blockIdx.x;
    int wave = threadIdx.x >> 6;
    int lane = threadIdx.x & 63;
    int l = blockIdx.y * 4 + wave;
    if (k > l) return;
    const float* r1 = src + ((size_t)k * LL + l) * DIN;
    const float* r2 = src + ((size_t)l * LL + k) * DIN;
    float2 a = *(const float2*)(r1 + lane * 2);
    float2 b = *(const float2*)(r2 + lane * 2);
    float x0 = 0.5f * (a.x + b.x);
    float x1 = 0.5f * (a.y + b.y);
    float s = x0 + x1, ss = x0 * x0 + x1 * x1;
    #pragma unroll
    for (int m = 1; m < 64; m <<= 1) { s += __shfl_xor(s, m); ss += __shfl_xor(ss, m); }
    float mean = s * (1.0f / DIN);
    float var  = ss * (1.0f / DIN) - mean * mean;
    float rstd = rsqrtf(var + EPS);
    int d0 = lane * 2;
    float n0 = g_norm[d0]     * (x0 - mean) * rstd + bt_norm[d0];
    float n1 = g_norm[d0 + 1] * (x1 - mean) * rstd + bt_norm[d0 + 1];
    float4 w0 = *(const float4*)(Wp + d0 * HH);
    float4 w1 = *(const float4*)(Wp + d0 * HH + HH);
    float p0 = n0 * w0.x + n1 * w1.x;
    float p1 = n0 * w0.y + n1 * w1.y;
    float p2 = n0 * w0.z + n1 * w1.z;
    float p3 = n0 * w0.w + n1 * w1.w;
    #pragma unroll
    for (int m = 1; m < 64; m <<= 1) {
        p0 += __shfl_xor(p0, m); p1 += __shfl_xor(p1, m);
        p2 += __shfl_xor(p2, m); p3 += __shfl_xor(p3, m);
    }
    int hh = lane & 3;
    float pv = (hh == 0 ? p0 : hh == 1 ? p1 : hh == 2 ? p2 : p3) + bp[hh];
    if (lane < 4)                 logits[((size_t)l * HH + hh) * LL + k] = pv;
    else if (lane < 8 && k != l)  logits[((size_t)k * HH + hh) * LL + l] = pv;
}

// ---------------------------------------------------------------- K2: softmax over k, bf16 out [h][l][k]
__global__ __launch_bounds__(256) void k2_softmax(
    const float* __restrict__ logits, short* __restrict__ attn_bf)
{
    int l = blockIdx.x;
    int h = threadIdx.x >> 6;
    int lane = threadIdx.x & 63;
    const float* row = logits + ((size_t)l * HH + h) * LL;
    float v[6];
    float mx = -1e30f;
    #pragma unroll
    for (int j = 0; j < 6; j++) { v[j] = row[lane + 64 * j]; mx = fmaxf(mx, v[j]); }
    #pragma unroll
    for (int m = 1; m < 64; m <<= 1) mx = fmaxf(mx, __shfl_xor(mx, m));
    float sum = 0.f;
    #pragma unroll
    for (int j = 0; j < 6; j++) { v[j] = __expf(v[j] - mx); sum += v[j]; }
    #pragma unroll
    for (int m = 1; m < 64; m <<= 1) sum += __shfl_xor(sum, m);
    float inv = 1.0f / sum;
    short* orow = attn_bf + ((size_t)h * LL + l) * LL;
    #pragma unroll
    for (int j = 0; j < 6; j++) orow[lane + 64 * j] = f2bf(v[j] * inv);
}

// ---------------------------------------------------------------- K3: v = LN(tgt)@Wm+bm -> bf16 [h][k][n*16+c]
// MFMA: one 16-row x 64-col tile per wave per iteration; Wm frags register-resident.
__global__ __launch_bounds__(256) void k3_v(
    const float* __restrict__ tgt, const float* __restrict__ Wm,
    const float* __restrict__ bm, const float* __restrict__ g1,
    const float* __restrict__ bt1, short* __restrict__ vt_bf)
{
    int tid = threadIdx.x, wave = tid >> 6, lane = tid & 63;
    int c15 = lane & 15, g = lane >> 4;
    bf16x8 wb[2][4];
    #pragma unroll
    for (int kf = 0; kf < 2; kf++)
        #pragma unroll
        for (int nt = 0; nt < 4; nt++) {
            bf16x8 w;
            #pragma unroll
            for (int i = 0; i < 8; i++) {
                int k = kf * 32 + g * 8 + i;
                w[i] = f2bf(Wm[k * DOUT + c15 * HH + nt]);
            }
            wb[kf][nt] = w;
        }
    float bmr[4];
    #pragma unroll
    for (int nt = 0; nt < 4; nt++) bmr[nt] = bm[c15 * HH + nt];
    float g1a[8], g1b[8], bta[8], btb[8];
    #pragma unroll
    for (int i = 0; i < 8; i++) {
        g1a[i] = g1[g * 8 + i];       bta[i] = bt1[g * 8 + i];
        g1b[i] = g1[32 + g * 8 + i];  btb[i] = bt1[32 + g * 8 + i];
    }
    const f32x4 zero = {0.f, 0.f, 0.f, 0.f};
    int gwave = blockIdx.x * 4 + wave;
    int nwaves = gridDim.x * 4;
    const int NT = NN * LL / 16;
    for (int t = gwave; t < NT; t += nwaves) {
        int r0 = t * 16;
        const float* tb = tgt + (size_t)r0 * DOUT + c15 * DOUT + g * 8;
        float4 xa = *(const float4*)(tb);
        float4 xb = *(const float4*)(tb + 4);
        float4 xc = *(const float4*)(tb + 32);
        float4 xd = *(const float4*)(tb + 36);
        float ya[8] = {xa.x, xa.y, xa.z, xa.w, xb.x, xb.y, xb.z, xb.w};
        float yb[8] = {xc.x, xc.y, xc.z, xc.w, xd.x, xd.y, xd.z, xd.w};
        float s = 0.f, ss = 0.f;
        #pragma unroll
        for (int i = 0; i < 8; i++) {
            s += ya[i] + yb[i];
            ss += ya[i] * ya[i] + yb[i] * yb[i];
        }
        s  += __shfl_xor(s, 16);  s  += __shfl_xor(s, 32);
        ss += __shfl_xor(ss, 16); ss += __shfl_xor(ss, 32);
        float mean = s * (1.0f / DOUT);
        float var  = ss * (1.0f / DOUT) - mean * mean;
        float rstd = rsqrtf(var + EPS);
        bf16x8 a0, a1;
        #pragma unroll
        for (int i = 0; i < 8; i++) {
            a0[i] = f2bf(g1a[i] * (ya[i] - mean) * rstd + bta[i]);
            a1[i] = f2bf(g1b[i] * (yb[i] - mean) * rstd + btb[i]);
        }
        f32x4 acc[4];
        #pragma unroll
        for (int nt = 0; nt < 4; nt++) {
            acc[nt] = MFMA16(a0, wb[0][nt], zero);
            acc[nt] = MFMA16(a1, wb[1][nt], acc[nt]);
        }
        int n = r0 / LL, k0 = r0 % LL;
        #pragma unroll
        for (int nt = 0; nt < 4; nt++)
            #pragma unroll
            for (int j = 0; j < 4; j++) {
                int k = k0 + g * 4 + j;
                vt_bf[((size_t)(nt * LL + k)) * (NN * CC) + n * CC + c15] =
                    f2bf(acc[nt][j] + bmr[nt]);
            }
    }
}

// ---------------------------------------------------------------- K4: einsum via MFMA per head
// C_h[l=384][m=64-tile] = sum_k attn_bf[h][l][k] * vt_bf[h][k][m0+m]; BK=32
// v2: register-staged async prefetch — next K-tile's global loads are issued
// right after the produce-barrier and fly during the 24-MFMA phase (T14/T3).
#define K4S 56   // LDS row stride in elems (112 B: 16B-aligned, 8 distinct bank starts)
__global__ __launch_bounds__(256, 3) void k4_mfma(
    const short* __restrict__ attn_bf, const short* __restrict__ vt_bf,
    short* __restrict__ o_bf)
{
    __shared__ short As[LL * K4S];   // 43008 B
    __shared__ short Bs[64 * K4S];   // 7168 B
    int h = blockIdx.y;
    int m0 = blockIdx.x * 64;
    int tid = threadIdx.x, wave = tid >> 6, lane = tid & 63;
    int c15 = lane & 15, g = lane >> 4;
    f32x4 acc[6][4];
    #pragma unroll
    for (int i = 0; i < 6; i++)
        #pragma unroll
        for (int nt = 0; nt < 4; nt++) acc[i][nt] = (f32x4){0.f, 0.f, 0.f, 0.f};

    // per-thread staging ownership
    int la = tid >> 2;             // A row base (0..63), rows la + 64*it
    int k8 = (tid & 3) * 8;        // A k-subchunk
    int mB = tid & 63;             // B column
    int kgB = tid >> 6;            // B k-group (0..3), 8 k's each

    bf16x8 aR[6];
    int bP[4];
    auto loadT = [&](int k0c) {
        #pragma unroll
        for (int it = 0; it < 6; it++)
            aR[it] = *(const bf16x8*)(attn_bf +
                      ((size_t)(h * LL) + la + 64 * it) * LL + k0c + k8);
        const short* vb = vt_bf + ((size_t)(h * LL + k0c + kgB * 8)) * (NN * CC) + m0 + mB;
        short t[8];
        #pragma unroll
        for (int j = 0; j < 8; j++) t[j] = vb[(size_t)j * (NN * CC)];
        #pragma unroll
        for (int j = 0; j < 4; j++)
            bP[j] = (int)(unsigned short)t[2 * j] | ((int)(unsigned short)t[2 * j + 1] << 16);
    };

    loadT(0);
    for (int k0 = 0; k0 < LL; k0 += 32) {
        __syncthreads();           // consume: previous MFMA reads done (no-op first iter)
        #pragma unroll
        for (int it = 0; it < 6; it++)
            *(bf16x8*)(As + (la + 64 * it) * K4S + k8) = aR[it];
        #pragma unroll
        for (int j = 0; j < 4; j++)
            *(int*)(Bs + mB * K4S + kgB * 8 + 2 * j) = bP[j];
        __syncthreads();           // produce: staging visible
        if (k0 + 32 < LL) loadT(k0 + 32);   // in flight during MFMA phase

        bf16x8 bfr[4];
        #pragma unroll
        for (int nt = 0; nt < 4; nt++)
            bfr[nt] = *(const bf16x8*)(Bs + (nt * 16 + c15) * K4S + g * 8);
        #pragma unroll
        for (int i = 0; i < 6; i++) {
            int l = (wave + 4 * i) * 16 + c15;
            bf16x8 afr = *(const bf16x8*)(As + l * K4S + g * 8);
            #pragma unroll
            for (int nt = 0; nt < 4; nt++)
                acc[i][nt] = MFMA16(afr, bfr[nt], acc[i][nt]);
        }
    }
    // epilogue: o_bf[(n*LL+l)][h*16+c]
    #pragma unroll
    for (int i = 0; i < 6; i++) {
        int l = (wave + 4 * i) * 16 + g * 4;
        #pragma unroll
        for (int nt = 0; nt < 4; nt++) {
            int n = (m0 >> 4) + nt;
            #pragma unroll
            for (int r = 0; r < 4; r++)
                o_bf[((size_t)n * LL + l + r) * DOUT + h * 16 + c15] = f2bf(acc[i][nt][r]);
        }
    }
}

// ---------------------------------------------------------------- K5: fused tail (Wo+res+LN+FFN+res), MFMA
// Round-3 measured-best version (46 µs): per-wave 16-row tiles, padded strides.
// (Conflict counter is dominated by the once-per-block staging loop — harmless.)
#define W1TS 72    // 144 B rows
#define W2TS 264   // 528 B rows
#define K5_LDS ((DFF * W1TS + DOUT * W2TS + 8 * 16 * W2TS) * 2)
__global__ __launch_bounds__(512) void k5_tail(
    const short* __restrict__ o_bf, const float* __restrict__ tgt,
    const float* __restrict__ Wo, const float* __restrict__ bo,
    const float* __restrict__ W1, const float* __restrict__ b1,
    const float* __restrict__ W2, const float* __restrict__ b2,
    const float* __restrict__ g2, const float* __restrict__ bt2,
    float* __restrict__ out)
{
    extern __shared__ short smem[];
    short* W1T = smem;                       // [p=ff][k=d], stride W1TS
    short* W2T = W1T + DFF * W1TS;           // [n=d][k=ff], stride W2TS
    short* Fl  = W2T + DOUT * W2TS;          // per-wave [16][W2TS]
    int tid = threadIdx.x, wave = tid >> 6, lane = tid & 63;
    int c15 = lane & 15, g = lane >> 4;

    // stage transposed weights (once per block)
    for (int e = tid; e < DOUT * DFF; e += 512) {
        int k = e >> 8, p = e & 255;
        W1T[p * W1TS + k] = f2bf(W1[e]);        // W1[k*DFF+p]
        int k2 = e >> 6, n = e & 63;
        W2T[n * W2TS + k2] = f2bf(W2[e]);       // W2[k2*DOUT+n]
    }
    // preload Wo B-frags (rows permuted: o cols are h*16+c <-> Wo row c*4+h)
    bf16x8 woB[2][4];
    #pragma unroll
    for (int kf = 0; kf < 2; kf++)
        #pragma unroll
        for (int nt = 0; nt < 4; nt++) {
            bf16x8 w;
            #pragma unroll
            for (int i2 = 0; i2 < 8; i2++) {
                int k = kf * 32 + g * 8 + i2;
                int rj = (k & 15) * 4 + (k >> 4);
                w[i2] = f2bf(Wo[rj * DOUT + nt * 16 + c15]);
            }
            woB[kf][nt] = w;
        }
    float bor[4], b2r[4], g2r[4], bt2r[4], b1r[16];
    #pragma unroll
    for (int nt = 0; nt < 4; nt++) {
        bor[nt]  = bo[nt * 16 + c15];  b2r[nt]  = b2[nt * 16 + c15];
        g2r[nt]  = g2[nt * 16 + c15];  bt2r[nt] = bt2[nt * 16 + c15];
    }
    #pragma unroll
    for (int nt = 0; nt < 16; nt++) b1r[nt] = b1[nt * 16 + c15];
    __syncthreads();

    short* Fw = Fl + wave * 16 * W2TS;
    int gwave = blockIdx.x * 8 + wave;
    const f32x4 zero = {0.f, 0.f, 0.f, 0.f};

    for (int it = 0; it < 6; it++) {
        int r0 = (gwave * 6 + it) * 16;
        // ---- stage1: X = tgt + o@Wo + bo (C-layout frags)
        const short* ob = o_bf + (size_t)r0 * DOUT;
        bf16x8 oa0 = *(const bf16x8*)(ob + c15 * DOUT + g * 8);
        bf16x8 oa1 = *(const bf16x8*)(ob + c15 * DOUT + 32 + g * 8);
        f32x4 X[4];
        #pragma unroll
        for (int nt = 0; nt < 4; nt++) {
            X[nt] = MFMA16(oa0, woB[0][nt], zero);
            X[nt] = MFMA16(oa1, woB[1][nt], X[nt]);
        }
        const float* tb = tgt + (size_t)r0 * DOUT;
        #pragma unroll
        for (int nt = 0; nt < 4; nt++)
            #pragma unroll
            for (int j = 0; j < 4; j++)
                X[nt][j] += tb[(g * 4 + j) * DOUT + nt * 16 + c15] + bor[nt];
        // ---- stage2: LN over d (frag rows spread across 16-lane groups)
        #pragma unroll
        for (int j = 0; j < 4; j++) {
            float s  = X[0][j] + X[1][j] + X[2][j] + X[3][j];
            float ss = X[0][j]*X[0][j] + X[1][j]*X[1][j] + X[2][j]*X[2][j] + X[3][j]*X[3][j];
            #pragma unroll
            for (int m = 1; m < 16; m <<= 1) { s += __shfl_xor(s, m); ss += __shfl_xor(ss, m); }
            float mean = s * (1.0f / DOUT);
            float var  = ss * (1.0f / DOUT) - mean * mean;
            float rstd = rsqrtf(var + EPS);
            #pragma unroll
            for (int nt = 0; nt < 4; nt++) {
                float y = g2r[nt] * (X[nt][j] - mean) * rstd + bt2r[nt];
                Fw[(g * 4 + j) * W2TS + nt * 16 + c15] = f2bf(y);
            }
        }
        // ---- stage3: F = relu(Y@W1 + b1)
        bf16x8 ya0 = *(const bf16x8*)(Fw + c15 * W2TS + g * 8);
        bf16x8 ya1 = *(const bf16x8*)(Fw + c15 * W2TS + 32 + g * 8);
        f32x4 Fa[16];
        #pragma unroll
        for (int nt = 0; nt < 16; nt++) {
            bf16x8 wb0 = *(const bf16x8*)(W1T + (nt * 16 + c15) * W1TS + g * 8);
            bf16x8 wb1 = *(const bf16x8*)(W1T + (nt * 16 + c15) * W1TS + 32 + g * 8);
            Fa[nt] = MFMA16(ya0, wb0, zero);
            Fa[nt] = MFMA16(ya1, wb1, Fa[nt]);
        }
        #pragma unroll
        for (int nt = 0; nt < 16; nt++)
            #pragma unroll
            for (int j = 0; j < 4; j++)
                Fw[(g * 4 + j) * W2TS + nt * 16 + c15] = f2bf(fmaxf(Fa[nt][j] + b1r[nt], 0.f));
        // ---- stage4: out = X + F@W2 + b2
        bf16x8 fa[8];
        #pragma unroll
        for (int kf = 0; kf < 8; kf++)
            fa[kf] = *(const bf16x8*)(Fw + c15 * W2TS + kf * 32 + g * 8);
        #pragma unroll
        for (int nt = 0; nt < 4; nt++)
            #pragma unroll
            for (int kf = 0; kf < 8; kf++) {
                bf16x8 wb = *(const bf16x8*)(W2T + (nt * 16 + c15) * W2TS + kf * 32 + g * 8);
                X[nt] = MFMA16(fa[kf], wb, X[nt]);
            }
        float* outb = out + (size_t)r0 * DOUT;
        #pragma unroll
        for (int nt = 0; nt < 4; nt++)
            #pragma unroll
            for (int j = 0; j < 4; j++)
                outb[(g * 4 + j) * DOUT + nt * 16 + c15] = X[nt][j] + b2r[nt];
    }
}

// ---------------------------------------------------------------- launch
extern "C" void kernel_launch(void* const* d_in, const int* in_sizes, int n_in,
                              void* d_out, int out_size, void* d_ws, size_t ws_size,
                              hipStream_t stream)
{
    (void)in_sizes; (void)n_in; (void)out_size; (void)ws_size;
    const float* src     = (const float*)d_in[0];
    const float* tgt     = (const float*)d_in[1];
    const float* Wp      = (const float*)d_in[2];
    const float* bp      = (const float*)d_in[3];
    const float* Wm      = (const float*)d_in[4];
    const float* bm      = (const float*)d_in[5];
    const float* Wo      = (const float*)d_in[6];
    const float* bo      = (const float*)d_in[7];
    const float* W1      = (const float*)d_in[8];
    const float* b1      = (const float*)d_in[9];
    const float* W2      = (const float*)d_in[10];
    const float* b2      = (const float*)d_in[11];
    const float* g_norm  = (const float*)d_in[12];
    const float* bt_norm = (const float*)d_in[13];
    const float* g1      = (const float*)d_in[14];
    const float* bt1     = (const float*)d_in[15];
    const float* g2      = (const float*)d_in[16];
    const float* bt2     = (const float*)d_in[17];
    float* out = (float*)d_out;
    float* ws  = (float*)d_ws;

    float* logits  = ws;                                  // 589824 f32
    short* attn_bf = (short*)(ws + 589824);               // [h][l][k] 589824 bf16
    short* vt_bf   = attn_bf + 589824;                    // [h][k][n*16+c] 12582912 bf16
    short* o_bf    = vt_bf + 12582912;                    // [n*384+l][h*16+c] 12582912 bf16

    hipFuncSetAttribute((const void*)k5_tail,
                        hipFuncAttributeMaxDynamicSharedMemorySize, K5_LDS);

    k1_logits <<<dim3(LL, LL / 4), 256, 0, stream>>>(src, Wp, bp, g_norm, bt_norm, logits);
    k2_softmax<<<LL, 256, 0, stream>>>(logits, attn_bf);
    k3_v      <<<1024, 256, 0, stream>>>(tgt, Wm, bm, g1, bt1, vt_bf);
    k4_mfma   <<<dim3((NN * CC) / 64, HH), 256, 0, stream>>>(attn_bf, vt_bf, o_bf);
    k5_tail   <<<256, 512, K5_LDS, stream>>>(o_bf, tgt, Wo, bo, W1, b1, W2, b2, g2, bt2, out);
}